// Round 4
// baseline (602.862 us; speedup 1.0000x reference)
//
#include <hip/hip_runtime.h>
#include <math.h>

typedef unsigned short ushort_t;
typedef unsigned int uint_t;
typedef __attribute__((ext_vector_type(8))) short short8;
typedef __attribute__((ext_vector_type(4))) float floatx4;

// Problem dims
constexpr int B = 8;
constexpr int S = 2048;
constexpr int D = 512;
constexpr int BS = B * S;          // 16384 rows
constexpr float LN_EPS = 1e-5f;
constexpr float ATTN_SCALE = 0.04419417382415922f;  // 1/sqrt(512)

// R5 lesson: global_load_lds staging corrupted post-warm replays on this
// toolchain -> VGPR reg-staging only. Do NOT alias Fb onto CDb/NXb.
// R6 lesson (848 us): 128x128/BK=64 quartered block count (PV 1 block/CU) ->
// latency fully exposed. Tile growth needs TLP or in-block pipelining.
// R7 lesson (545 us): prefetch-to-regs alone ~neutral.
// R8 lesson (539 us): single-barrier dbuf only -6 us; cores sit at ~300 TF
// with no pipe saturated. Gate FETCH 164 MB vs ~70 MB unique input: the 4
// n-blocks sharing an A-panel land on different XCDs and re-fetch from HBM.
// R9: (a) T1 XCD-aware bijective block swizzle on all GEMMs (grids %8==0) —
// n-siblings of one A-panel become XCD-co-resident; qk/ffn chunk working
// sets (~3 MB) fit the 4 MB per-XCD L2. (b) PV (K=2048, most barriers in the
// pipeline) moves to BK=64 at the same 128x64 tile: 16 MFMA/barrier/wave,
// 32 barriers instead of 64, LDS 55.3 KB keeps 2 blocks/CU (= grid cap, no
// R6 starvation). gemm2 stays BK=32 (4 blocks/CU).
// Xb aliasing (slot0): qk g reads batches of Xb that pv g-1 hasn't
// overwritten; stream-ordered => safe.

// ---------------------------------------------------------------------------
// bf16 helpers (RNE)
// ---------------------------------------------------------------------------
__device__ __forceinline__ ushort_t f2bf(float f) {
    union { float f; uint_t u; } x; x.f = f;
    uint_t r = x.u + 0x7fffu + ((x.u >> 16) & 1u);
    return (ushort_t)(r >> 16);
}
__device__ __forceinline__ float bf2f(ushort_t h) {
    union { uint_t u; float f; } y; y.u = ((uint_t)h) << 16;
    return y.f;
}
__device__ __forceinline__ short8 pack8(float4 a, float4 b) {
    short8 p;
    p[0] = (short)f2bf(a.x); p[1] = (short)f2bf(a.y);
    p[2] = (short)f2bf(a.z); p[3] = (short)f2bf(a.w);
    p[4] = (short)f2bf(b.x); p[5] = (short)f2bf(b.y);
    p[6] = (short)f2bf(b.z); p[7] = (short)f2bf(b.w);
    return p;
}

// XCD-aware bijective swizzle (T1): flat id F -> logical tile L so that each
// XCD (F%8) owns a contiguous chunk of logical tiles. Requires nwg%8==0
// (all GEMM grids here: 512/1024). Decode x-fastest.
#define SWZ_DECODE(bx, by, bz)                                                 \
    int bx, by, bz;                                                            \
    {                                                                          \
        const int gx = gridDim.x, gy = gridDim.y;                              \
        const int nwg = gx * gy * (int)gridDim.z;                              \
        const int F = blockIdx.x + gx * (blockIdx.y + gy * blockIdx.z);        \
        const int L = (F & 7) * (nwg >> 3) + (F >> 3);                         \
        bx = L % gx;                                                           \
        const int l2 = L / gx;                                                 \
        by = l2 % gy;                                                          \
        bz = l2 / gy;                                                          \
    }

// ---------------------------------------------------------------------------
// Reductions (256-thread blocks = 4 waves of 64)
// ---------------------------------------------------------------------------
__device__ __forceinline__ float blk_reduce_sum(float v, float* sm) {
#pragma unroll
    for (int o = 32; o; o >>= 1) v += __shfl_down(v, o, 64);
    __syncthreads();
    if ((threadIdx.x & 63) == 0) sm[threadIdx.x >> 6] = v;
    __syncthreads();
    return sm[0] + sm[1] + sm[2] + sm[3];
}
__device__ __forceinline__ float blk_reduce_max(float v, float* sm) {
#pragma unroll
    for (int o = 32; o; o >>= 1) v = fmaxf(v, __shfl_down(v, o, 64));
    __syncthreads();
    if ((threadIdx.x & 63) == 0) sm[threadIdx.x >> 6] = v;
    __syncthreads();
    return fmaxf(fmaxf(sm[0], sm[1]), fmaxf(sm[2], sm[3]));
}

// ---------------------------------------------------------------------------
// fp32 [R][C] -> bf16 [C][R] transpose+convert; batched via blockIdx.z (z*R*C)
// Optionally also emits the straight (non-transposed) bf16 copy into out2.
// ---------------------------------------------------------------------------
__global__ __launch_bounds__(256) void transpose_cvt(
    const float* __restrict__ in, ushort_t* __restrict__ out, int R, int C,
    ushort_t* __restrict__ out2) {
    __shared__ float tl[32][33];
    const size_t zoff = (size_t)blockIdx.z * R * C;
    const int tx = threadIdx.x & 31, ty = threadIdx.x >> 5;  // ty 0..7
    const int c0 = blockIdx.x * 32, r0 = blockIdx.y * 32;
#pragma unroll
    for (int i = 0; i < 4; i++) {
        const float v = in[zoff + (size_t)(r0 + ty + i * 8) * C + c0 + tx];
        tl[ty + i * 8][tx] = v;
        if (out2) out2[zoff + (size_t)(r0 + ty + i * 8) * C + c0 + tx] = f2bf(v);
    }
    __syncthreads();
#pragma unroll
    for (int i = 0; i < 4; i++)
        out[zoff + (size_t)(c0 + ty + i * 8) * R + r0 + tx] = f2bf(tl[tx][ty + i * 8]);
}

// ---------------------------------------------------------------------------
// Shared index preamble for 128-wide-M cores (4 waves)
// ---------------------------------------------------------------------------
#define IDX128()                                                               \
    const int t = threadIdx.x;                                                 \
    const int sr = t >> 2;               /* 0..63 */                           \
    const int sc = (t & 3) * 8;          /* 0,8,16,24 */                       \
    const int lane = t & 63, w = t >> 6;                                       \
    const int fr = lane & 15, fq = lane >> 4;

// MFMA stage from explicit LDS buffer pointers (128x128 core: 2x2 waves)
#define MFMA16(Asp, Bsp)                                                       \
    {                                                                          \
        short8 af[4], bfg[4];                                                  \
        _Pragma("unroll") for (int i = 0; i < 4; i++) {                        \
            af[i]  = *(const short8*)&(Asp)[(wm + i * 16 + fr) * 40 + fq * 8]; \
            bfg[i] = *(const short8*)&(Bsp)[(wn + i * 16 + fr) * 40 + fq * 8]; \
        }                                                                      \
        _Pragma("unroll") for (int i = 0; i < 4; i++)                          \
            _Pragma("unroll") for (int j = 0; j < 4; j++)                      \
                acc[i][j] = __builtin_amdgcn_mfma_f32_16x16x32_bf16(           \
                    af[i], bfg[j], acc[i][j], 0, 0, 0);                        \
    }

// ---------------------------------------------------------------------------
// Gate GEMM: 128x128 tile, BK=32, double-buffered, XCD-swizzled.
// A = concat(NX,CD) fp32 (pack to bf16 at LDS-write time), B = WgT bf16.
// Epilogue: g = sigmoid(acc + bg); Fb = bf16(g*NX + (1-g)*CD). M=BS,N=512,K=1024
// ---------------------------------------------------------------------------
__global__ __launch_bounds__(256) void gate_gemm(
    const float* __restrict__ NX, const float* __restrict__ CD,
    const ushort_t* __restrict__ WgT, const float* __restrict__ bg,
    ushort_t* __restrict__ Fb) {
    __shared__ ushort_t As[2][128 * 40];
    __shared__ ushort_t Bs[2][128 * 40];
    SWZ_DECODE(bx, by, bz);
    (void)bz;
    IDX128();
    const int m0 = by * 128, n0 = bx * 128;
    const int wm = (w >> 1) * 64, wn = (w & 1) * 64;
    floatx4 acc[4][4];
#pragma unroll
    for (int i = 0; i < 4; i++)
#pragma unroll
        for (int j = 0; j < 4; j++) {
            acc[i][j][0] = 0.f; acc[i][j][1] = 0.f;
            acc[i][j][2] = 0.f; acc[i][j][3] = 0.f;
        }
    const ushort_t* Bb = WgT + (size_t)n0 * 1024;

    float4 f00, f01, f10, f11;
    int4 b0, b1;
    // k = 0 (NX): load + write buf0
    {
        const float* p0 = NX + (size_t)(m0 + sr) * 512 + sc;
        const float* p1 = NX + (size_t)(m0 + sr + 64) * 512 + sc;
        f00 = *(const float4*)p0;  f01 = *(const float4*)(p0 + 4);
        f10 = *(const float4*)p1;  f11 = *(const float4*)(p1 + 4);
        b0 = *(const int4*)(Bb + (size_t)sr * 1024 + sc);
        b1 = *(const int4*)(Bb + (size_t)(sr + 64) * 1024 + sc);
        *(short8*)&As[0][sr * 40 + sc] = pack8(f00, f01);
        *(short8*)&As[0][(sr + 64) * 40 + sc] = pack8(f10, f11);
        *(int4*)&Bs[0][sr * 40 + sc] = b0;
        *(int4*)&Bs[0][(sr + 64) * 40 + sc] = b1;
    }
    // k = 32 (NX): load into regs
    {
        const float* p0 = NX + (size_t)(m0 + sr) * 512 + 32 + sc;
        const float* p1 = NX + (size_t)(m0 + sr + 64) * 512 + 32 + sc;
        f00 = *(const float4*)p0;  f01 = *(const float4*)(p0 + 4);
        f10 = *(const float4*)p1;  f11 = *(const float4*)(p1 + 4);
        b0 = *(const int4*)(Bb + (size_t)sr * 1024 + 32 + sc);
        b1 = *(const int4*)(Bb + (size_t)(sr + 64) * 1024 + 32 + sc);
    }
    __syncthreads();

    int cur = 0;
    for (int k0 = 0; k0 < 1024; k0 += 32) {
        MFMA16(As[cur], Bs[cur]);
        const int kn = k0 + 32;
        if (kn < 1024) {
            *(short8*)&As[cur ^ 1][sr * 40 + sc] = pack8(f00, f01);
            *(short8*)&As[cur ^ 1][(sr + 64) * 40 + sc] = pack8(f10, f11);
            *(int4*)&Bs[cur ^ 1][sr * 40 + sc] = b0;
            *(int4*)&Bs[cur ^ 1][(sr + 64) * 40 + sc] = b1;
            const int kf = kn + 32;
            if (kf < 1024) {
                const float* Asrc = (kf < 512) ? NX : CD;
                const int kk = kf & 511;
                const float* p0 = Asrc + (size_t)(m0 + sr) * 512 + kk + sc;
                const float* p1 = Asrc + (size_t)(m0 + sr + 64) * 512 + kk + sc;
                f00 = *(const float4*)p0;  f01 = *(const float4*)(p0 + 4);
                f10 = *(const float4*)p1;  f11 = *(const float4*)(p1 + 4);
                b0 = *(const int4*)(Bb + (size_t)sr * 1024 + kf + sc);
                b1 = *(const int4*)(Bb + (size_t)(sr + 64) * 1024 + kf + sc);
            }
        }
        __syncthreads();
        cur ^= 1;
    }

#pragma unroll
    for (int i = 0; i < 4; i++) {
#pragma unroll
        for (int j = 0; j < 4; j++) {
#pragma unroll
            for (int r = 0; r < 4; r++) {
                const int m = m0 + wm + i * 16 + fq * 4 + r;
                const int n = n0 + wn + j * 16 + fr;
                const float z = acc[i][j][r] + bg[n];
                const float g = 1.f / (1.f + expf(-z));
                const size_t idx = (size_t)m * 512 + n;
                Fb[idx] = f2bf(g * NX[idx] + (1.f - g) * CD[idx]);
            }
        }
    }
}

// ---------------------------------------------------------------------------
// gemm2: 128x128 tile, BK=32, pure bf16, double-buffered, XCD-swizzled.
// For qk + ffn (grids >= 2 blocks/CU, LDS 40,960 B -> 4 blocks/CU).
// EPI: 0 = scale + bf16 store; 1 = +bias, exact gelu, bf16 store;
//      2 = fp32 accumulate in place (T += acc [+ bias if init])
// ---------------------------------------------------------------------------
template <int EPI>
__global__ __launch_bounds__(256) void gemm2_std(
    const ushort_t* __restrict__ A, int lda, long sAz,
    const ushort_t* __restrict__ Bt, int ldb, long sBz,
    void* __restrict__ Cv, int ldc, long sCz,
    int K, const float* __restrict__ bias, float scale, int init) {
    __shared__ ushort_t As[2][128 * 40];
    __shared__ ushort_t Bs[2][128 * 40];
    SWZ_DECODE(bx, by, bz);
    IDX128();
    const int m0 = by * 128, n0 = bx * 128;
    const int wm = (w >> 1) * 64, wn = (w & 1) * 64;
    floatx4 acc[4][4];
#pragma unroll
    for (int i = 0; i < 4; i++)
#pragma unroll
        for (int j = 0; j < 4; j++) {
            acc[i][j][0] = 0.f; acc[i][j][1] = 0.f;
            acc[i][j][2] = 0.f; acc[i][j][3] = 0.f;
        }
    const ushort_t* Ab = A + (size_t)bz * sAz + (size_t)m0 * lda;
    const ushort_t* Bb = Bt + (size_t)bz * sBz + (size_t)n0 * ldb;

    int4 a0 = *(const int4*)(Ab + (size_t)sr * lda + sc);
    int4 a1 = *(const int4*)(Ab + (size_t)(sr + 64) * lda + sc);
    int4 b0 = *(const int4*)(Bb + (size_t)sr * ldb + sc);
    int4 b1 = *(const int4*)(Bb + (size_t)(sr + 64) * ldb + sc);
    *(int4*)&As[0][sr * 40 + sc] = a0;
    *(int4*)&As[0][(sr + 64) * 40 + sc] = a1;
    *(int4*)&Bs[0][sr * 40 + sc] = b0;
    *(int4*)&Bs[0][(sr + 64) * 40 + sc] = b1;
    if (32 < K) {
        a0 = *(const int4*)(Ab + (size_t)sr * lda + 32 + sc);
        a1 = *(const int4*)(Ab + (size_t)(sr + 64) * lda + 32 + sc);
        b0 = *(const int4*)(Bb + (size_t)sr * ldb + 32 + sc);
        b1 = *(const int4*)(Bb + (size_t)(sr + 64) * ldb + 32 + sc);
    }
    __syncthreads();

    int cur = 0;
    for (int k0 = 0; k0 < K; k0 += 32) {
        MFMA16(As[cur], Bs[cur]);
        const int kn = k0 + 32;
        if (kn < K) {
            *(int4*)&As[cur ^ 1][sr * 40 + sc] = a0;
            *(int4*)&As[cur ^ 1][(sr + 64) * 40 + sc] = a1;
            *(int4*)&Bs[cur ^ 1][sr * 40 + sc] = b0;
            *(int4*)&Bs[cur ^ 1][(sr + 64) * 40 + sc] = b1;
            const int kf = kn + 32;
            if (kf < K) {
                a0 = *(const int4*)(Ab + (size_t)sr * lda + kf + sc);
                a1 = *(const int4*)(Ab + (size_t)(sr + 64) * lda + kf + sc);
                b0 = *(const int4*)(Bb + (size_t)sr * ldb + kf + sc);
                b1 = *(const int4*)(Bb + (size_t)(sr + 64) * ldb + kf + sc);
            }
        }
        __syncthreads();
        cur ^= 1;
    }

#pragma unroll
    for (int i = 0; i < 4; i++) {
#pragma unroll
        for (int j = 0; j < 4; j++) {
#pragma unroll
            for (int r = 0; r < 4; r++) {
                const int m = m0 + wm + i * 16 + fq * 4 + r;
                const int n = n0 + wn + j * 16 + fr;
                float v = acc[i][j][r];
                if (EPI == 0) {
                    ushort_t* C = (ushort_t*)Cv + (size_t)bz * sCz;
                    C[(size_t)m * ldc + n] = f2bf(v * scale);
                } else if (EPI == 1) {
                    const float x = v + bias[n];
                    const float gl = 0.5f * x * (1.f + erff(x * 0.70710678118654752f));
                    ushort_t* C = (ushort_t*)Cv;
                    C[(size_t)m * ldc + n] = f2bf(gl);
                } else {
                    float* T = (float*)Cv;
                    const size_t idx = (size_t)m * ldc + n;
                    T[idx] = T[idx] + v + (init ? bias[n] : 0.f);
                }
            }
        }
    }
}

// ---------------------------------------------------------------------------
// gemm3: 128x64 tile, BK=64, double-buffered, XCD-swizzled. For PV (K=2048:
// 16 MFMA/barrier/wave, 32 barriers). LDS 55,296 B -> 2 blocks/CU = grid cap.
// Stride 72 ushorts (144 B, 16B-aligned rows, distinct per-row bank starts).
// 4 waves stacked on M (wave tile 32x64).
// ---------------------------------------------------------------------------
template <int EPI>
__global__ __launch_bounds__(256) void gemm3_std(
    const ushort_t* __restrict__ A, int lda, long sAz,
    const ushort_t* __restrict__ Bt, int ldb, long sBz,
    void* __restrict__ Cv, int ldc, long sCz,
    int K, const float* __restrict__ bias, float scale, int init) {
    __shared__ ushort_t As[2][128 * 72];
    __shared__ ushort_t Bs[2][64 * 72];
    SWZ_DECODE(bx, by, bz);
    const int t = threadIdx.x;
    const int sr8 = t >> 3;              // 0..31
    const int sc8 = (t & 7) * 8;         // 0..56 shorts
    const int lane = t & 63, w = t >> 6;
    const int wm = w * 32;
    const int fr = lane & 15, fq = lane >> 4;
    const int m0 = by * 128, n0 = bx * 64;
    floatx4 acc[2][4];
#pragma unroll
    for (int i = 0; i < 2; i++)
#pragma unroll
        for (int j = 0; j < 4; j++) {
            acc[i][j][0] = 0.f; acc[i][j][1] = 0.f;
            acc[i][j][2] = 0.f; acc[i][j][3] = 0.f;
        }
    const ushort_t* Ab = A + (size_t)bz * sAz + (size_t)m0 * lda;
    const ushort_t* Bb = Bt + (size_t)bz * sBz + (size_t)n0 * ldb;

    int4 ra[4], rb[2];
#define G3_LD(k)                                                               \
    {                                                                          \
        _Pragma("unroll") for (int i = 0; i < 4; i++)                          \
            ra[i] = *(const int4*)(Ab + (size_t)(sr8 + i * 32) * lda + (k) + sc8); \
        _Pragma("unroll") for (int i = 0; i < 2; i++)                          \
            rb[i] = *(const int4*)(Bb + (size_t)(sr8 + i * 32) * ldb + (k) + sc8); \
    }
#define G3_ST(buf)                                                             \
    {                                                                          \
        _Pragma("unroll") for (int i = 0; i < 4; i++)                          \
            *(int4*)&As[buf][(sr8 + i * 32) * 72 + sc8] = ra[i];               \
        _Pragma("unroll") for (int i = 0; i < 2; i++)                          \
            *(int4*)&Bs[buf][(sr8 + i * 32) * 72 + sc8] = rb[i];               \
    }

    G3_LD(0);
    G3_ST(0);
    if (64 < K) G3_LD(64);
    __syncthreads();

    int cur = 0;
    for (int k0 = 0; k0 < K; k0 += 64) {
#pragma unroll
        for (int kk = 0; kk < 2; kk++) {
            short8 af[2], bfg[4];
#pragma unroll
            for (int i = 0; i < 2; i++)
                af[i] = *(const short8*)&As[cur][(wm + i * 16 + fr) * 72 + kk * 32 + fq * 8];
#pragma unroll
            for (int j = 0; j < 4; j++)
                bfg[j] = *(const short8*)&Bs[cur][(j * 16 + fr) * 72 + kk * 32 + fq * 8];
#pragma unroll
            for (int i = 0; i < 2; i++)
#pragma unroll
                for (int j = 0; j < 4; j++)
                    acc[i][j] = __builtin_amdgcn_mfma_f32_16x16x32_bf16(
                        af[i], bfg[j], acc[i][j], 0, 0, 0);
        }
        const int kn = k0 + 64;
        if (kn < K) {
            G3_ST(cur ^ 1);
            if (kn + 64 < K) G3_LD(kn + 64);
        }
        __syncthreads();
        cur ^= 1;
    }

#pragma unroll
    for (int i = 0; i < 2; i++) {
#pragma unroll
        for (int j = 0; j < 4; j++) {
#pragma unroll
            for (int r = 0; r < 4; r++) {
                const int m = m0 + wm + i * 16 + fq * 4 + r;
                const int n = n0 + j * 16 + fr;
                float v = acc[i][j][r];
                if (EPI == 0) {
                    ushort_t* C = (ushort_t*)Cv + (size_t)bz * sCz;
                    C[(size_t)m * ldc + n] = f2bf(v * scale);
                } else if (EPI == 1) {
                    const float x = v + bias[n];
                    const float gl = 0.5f * x * (1.f + erff(x * 0.70710678118654752f));
                    ushort_t* C = (ushort_t*)Cv;
                    C[(size_t)m * ldc + n] = f2bf(gl);
                } else {
                    float* T = (float*)Cv;
                    const size_t idx = (size_t)m * ldc + n;
                    T[idx] = T[idx] + v + (init ? bias[n] : 0.f);
                }
            }
        }
    }
#undef G3_LD
#undef G3_ST
}

// ---------------------------------------------------------------------------
// Softmax over bf16 rows of 2048, in place
// ---------------------------------------------------------------------------
__global__ __launch_bounds__(256) void softmax_bf16(ushort_t* __restrict__ Sc) {
    __shared__ float sm[4];
    ushort_t* row = Sc + (size_t)blockIdx.x * 2048;
    const int t = threadIdx.x;
    ushort_t raw[8];
    *(int4*)raw = *(const int4*)(row + t * 8);
    float e[8];
    float mx = -1e30f;
#pragma unroll
    for (int j = 0; j < 8; j++) { e[j] = bf2f(raw[j]); mx = fmaxf(mx, e[j]); }
    mx = blk_reduce_max(mx, sm);
    float s = 0.f;
#pragma unroll
    for (int j = 0; j < 8; j++) { e[j] = expf(e[j] - mx); s += e[j]; }
    s = blk_reduce_sum(s, sm);
    const float inv = 1.f / s;
#pragma unroll
    for (int j = 0; j < 8; j++) raw[j] = f2bf(e[j] * inv);
    *(int4*)(row + t * 8) = *(const int4*)raw;
}

// ---------------------------------------------------------------------------
// LN1: q = LN(fused + attn) -> qf (fp32) and qb (bf16)
// ---------------------------------------------------------------------------
__global__ __launch_bounds__(256) void ln1_kernel(
    const ushort_t* __restrict__ Fb, const ushort_t* __restrict__ Ab,
    const float* __restrict__ g1, const float* __restrict__ be1,
    float* __restrict__ qf, ushort_t* __restrict__ qb) {
    __shared__ float sm[4];
    const size_t base = (size_t)blockIdx.x * 512;
    const int t = threadIdx.x;
    const float v0 = bf2f(Fb[base + t]) + bf2f(Ab[base + t]);
    const float v1 = bf2f(Fb[base + t + 256]) + bf2f(Ab[base + t + 256]);
    const float mu = blk_reduce_sum(v0 + v1, sm) * (1.f / 512.f);
    const float d0 = v0 - mu, d1 = v1 - mu;
    const float var = blk_reduce_sum(d0 * d0 + d1 * d1, sm) * (1.f / 512.f);
    const float rs = rsqrtf(var + LN_EPS);
    const float y0 = d0 * rs * g1[t] + be1[t];
    const float y1 = d1 * rs * g1[t + 256] + be1[t + 256];
    qf[base + t] = y0;          qf[base + t + 256] = y1;
    qb[base + t] = f2bf(y0);    qb[base + t + 256] = f2bf(y1);
}

// Final LN in place on fp32
__global__ __launch_bounds__(256) void ln2_kernel(
    float* __restrict__ T, const float* __restrict__ g,
    const float* __restrict__ be) {
    __shared__ float sm[4];
    const size_t base = (size_t)blockIdx.x * 512;
    const int t = threadIdx.x;
    const float v0 = T[base + t];
    const float v1 = T[base + t + 256];
    const float mu = blk_reduce_sum(v0 + v1, sm) * (1.f / 512.f);
    const float d0 = v0 - mu, d1 = v1 - mu;
    const float var = blk_reduce_sum(d0 * d0 + d1 * d1, sm) * (1.f / 512.f);
    const float rs = rsqrtf(var + LN_EPS);
    T[base + t] = d0 * rs * g[t] + be[t];
    T[base + t + 256] = d1 * rs * g[t + 256] + be[t + 256];
}

// ---------------------------------------------------------------------------
extern "C" void kernel_launch(void* const* d_in, const int* in_sizes, int n_in,
                              void* d_out, int out_size, void* d_ws, size_t ws_size,
                              hipStream_t stream) {
    const float* NX  = (const float*)d_in[0];
    const float* X   = (const float*)d_in[1];
    const float* CD  = (const float*)d_in[2];
    const float* Wg  = (const float*)d_in[3];
    const float* bg  = (const float*)d_in[4];
    const float* W1  = (const float*)d_in[5];
    const float* b1  = (const float*)d_in[6];
    const float* W2  = (const float*)d_in[7];
    const float* b2  = (const float*)d_in[8];
    const float* g1  = (const float*)d_in[9];
    const float* be1 = (const float*)d_in[10];
    const float* g2  = (const float*)d_in[11];
    const float* be2 = (const float*)d_in[12];

    // ws: 3 slots x 16,777,216 B = 50,331,648 B (proven-safe since R2)
    // slot0: Xb -> attnb (progressive, see header note) -> hbuf
    // slot1: Fb -> W1T/W2T;  slot2: WgT -> XbT -> qb
    // d_out: scores (bf16) -> qf (fp32, final)
    ushort_t* slot0 = (ushort_t*)d_ws;
    ushort_t* slot1 = (ushort_t*)((char*)d_ws + 16777216);
    ushort_t* slot2 = (ushort_t*)((char*)d_ws + 33554432);
    ushort_t* Xb    = slot0;                    // [8][2048][512] bf16
    ushort_t* attnb = slot0;
    ushort_t* hbuf  = slot0;
    ushort_t* Fb    = slot1;
    ushort_t* W1T   = slot1;                    // [1024][512] bf16, 1 MB
    ushort_t* W2T   = slot1 + 524288;           // [512][1024] bf16, 1 MB
    ushort_t* WgT   = slot2;                    // [512][1024] bf16, 1 MB
    ushort_t* XbT   = slot2;                    // [8][512][2048] bf16, 16.78 MB
    ushort_t* qb    = slot2;                    // [BS][512] bf16
    ushort_t* Scb   = (ushort_t*)d_out;         // 4 batches [S][S] bf16
    float*    qf    = (float*)d_out;

    // 1) Wg^T (slot2)
    transpose_cvt<<<dim3(512 / 32, 1024 / 32, 1), 256, 0, stream>>>(
        Wg, WgT, 1024, 512, nullptr);

    // 2) gated fusion -> Fb (128x128 dbuf core; fp32 A converted in staging)
    gate_gemm<<<dim3(4, 128), 256, 0, stream>>>(NX, CD, WgT, bg, Fb);

    // 3) X^T per batch into slot2 (WgT dead) — needed by PV;
    //    fused straight bf16 copy Xb into slot0 — needed by QK
    transpose_cvt<<<dim3(512 / 32, 2048 / 32, 8), 256, 0, stream>>>(
        X, XbT, 2048, 512, Xb);

    // 4) attention in 2 groups of 4 batches; scores in d_out
    for (int g = 0; g < 2; g++) {
        const size_t go = (size_t)g * 4 * S * 512;
        // QK: Sc = (Fb @ Xb^T) * scale (128x128 dbuf; 1024 blocks = 4/CU)
        gemm2_std<0><<<dim3(16, 16, 4), 256, 0, stream>>>(
            Fb + go, D, (long)S * D,
            Xb + go, D, (long)S * D,
            (void*)Scb, S, (long)S * S, D, nullptr, ATTN_SCALE, 0);
        softmax_bf16<<<4 * S, 256, 0, stream>>>(Scb);
        // PV: attn = P @ X  (128x64 BK=64 dbuf; 512 blocks = 2/CU)
        gemm3_std<0><<<dim3(8, 16, 4), 256, 0, stream>>>(
            Scb, S, (long)S * S,
            XbT + go, S, (long)D * S,
            (void*)(attnb + go), 512, (long)S * 512, S, nullptr, 1.f, 0);
    }

    // 5) q = LN(fused + attn): qf -> d_out (scores dead), qb -> slot2 (XbT dead)
    ln1_kernel<<<BS, 256, 0, stream>>>(Fb, attnb, g1, be1, qf, qb);

    // 6) weight transposes into slot1 (Fb dead after LN1)
    transpose_cvt<<<dim3(1024 / 32, 512 / 32, 1), 256, 0, stream>>>(
        W1, W1T, 512, 1024, nullptr);
    transpose_cvt<<<dim3(512 / 32, 1024 / 32, 1), 256, 0, stream>>>(
        W2, W2T, 1024, 512, nullptr);

    // 7) FFN in 2 halves; hidden half in slot0 (attnb dead); t accumulates in d_out
    for (int h = 0; h < 2; h++) {
        gemm2_std<1><<<dim3(4, 128), 256, 0, stream>>>(
            qb, 512, 0, W1T + (size_t)h * 512 * 512, 512, 0,
            (void*)hbuf, 512, 0, 512, b1 + h * 512, 1.f, 0);
        gemm2_std<2><<<dim3(4, 128), 256, 0, stream>>>(
            hbuf, 512, 0, W2T + h * 512, 1024, 0,
            (void*)qf, 512, 0, 512, b2, 1.f, h == 0 ? 1 : 0);
    }

    // 8) out = LN(t) in place in d_out
    ln2_kernel<<<BS, 256, 0, stream>>>(qf, g2, be2);
}

// Round 5
// 513.530 us; speedup vs baseline: 1.1740x; 1.1740x over previous
//
#include <hip/hip_runtime.h>
#include <math.h>

typedef unsigned short ushort_t;
typedef unsigned int uint_t;
typedef __attribute__((ext_vector_type(8))) short short8;
typedef __attribute__((ext_vector_type(4))) float floatx4;

// Problem dims
constexpr int B = 8;
constexpr int S = 2048;
constexpr int D = 512;
constexpr int BS = B * S;          // 16384 rows
constexpr float LN_EPS = 1e-5f;
constexpr float ATTN_SCALE = 0.04419417382415922f;  // 1/sqrt(512)

// R5 lesson: global_load_lds staging corrupted post-warm replays on this
// toolchain -> VGPR reg-staging only. Do NOT alias Fb onto CDb/NXb.
// R6 lesson (848 us): 128x128/BK=64 quartered block count (PV 1 block/CU) ->
// latency fully exposed. Tile growth needs TLP or in-block pipelining.
// R7 lesson (545 us): prefetch-to-regs alone ~neutral.
// R8 lesson (539 us): single-barrier dbuf only -6 us; no pipe saturated.
// R9 lesson (603 us): (a) T1 XCD swizzle GOOD — PV FETCH 24.6 MB vs 42 MB
// unique (L2 chunk capture), gate left the top-5; (b) PV BK=64/stride-72
// BAD — byte stride 144 = 4 banks mod 32 makes read bank-start 4*(fr+fq):
// 8-way conflict, SQ_LDS_BANK_CONFLICT 1.4e7, PV 84 us. Stride-40 (80 B =
// 20 banks, odd multiplier) is the proven low-conflict layout.
// R10: revert PV to BK=32/stride-40 dbuf core, keep swizzle everywhere.
// Xb aliasing (slot0): qk g reads batches of Xb that pv g-1 hasn't
// overwritten; stream-ordered => safe.

// ---------------------------------------------------------------------------
// bf16 helpers (RNE)
// ---------------------------------------------------------------------------
__device__ __forceinline__ ushort_t f2bf(float f) {
    union { float f; uint_t u; } x; x.f = f;
    uint_t r = x.u + 0x7fffu + ((x.u >> 16) & 1u);
    return (ushort_t)(r >> 16);
}
__device__ __forceinline__ float bf2f(ushort_t h) {
    union { uint_t u; float f; } y; y.u = ((uint_t)h) << 16;
    return y.f;
}
__device__ __forceinline__ short8 pack8(float4 a, float4 b) {
    short8 p;
    p[0] = (short)f2bf(a.x); p[1] = (short)f2bf(a.y);
    p[2] = (short)f2bf(a.z); p[3] = (short)f2bf(a.w);
    p[4] = (short)f2bf(b.x); p[5] = (short)f2bf(b.y);
    p[6] = (short)f2bf(b.z); p[7] = (short)f2bf(b.w);
    return p;
}

// XCD-aware bijective swizzle (T1): flat id F -> logical tile L so that each
// XCD (F%8) owns a contiguous chunk of logical tiles. Requires nwg%8==0
// (all GEMM grids here: 512/1024). Decode x-fastest.
#define SWZ_DECODE(bx, by, bz)                                                 \
    int bx, by, bz;                                                            \
    {                                                                          \
        const int gx = gridDim.x, gy = gridDim.y;                              \
        const int nwg = gx * gy * (int)gridDim.z;                              \
        const int F = blockIdx.x + gx * (blockIdx.y + gy * blockIdx.z);        \
        const int L = (F & 7) * (nwg >> 3) + (F >> 3);                         \
        bx = L % gx;                                                           \
        const int l2 = L / gx;                                                 \
        by = l2 % gy;                                                          \
        bz = l2 / gy;                                                          \
    }

// ---------------------------------------------------------------------------
// Reductions (256-thread blocks = 4 waves of 64)
// ---------------------------------------------------------------------------
__device__ __forceinline__ float blk_reduce_sum(float v, float* sm) {
#pragma unroll
    for (int o = 32; o; o >>= 1) v += __shfl_down(v, o, 64);
    __syncthreads();
    if ((threadIdx.x & 63) == 0) sm[threadIdx.x >> 6] = v;
    __syncthreads();
    return sm[0] + sm[1] + sm[2] + sm[3];
}
__device__ __forceinline__ float blk_reduce_max(float v, float* sm) {
#pragma unroll
    for (int o = 32; o; o >>= 1) v = fmaxf(v, __shfl_down(v, o, 64));
    __syncthreads();
    if ((threadIdx.x & 63) == 0) sm[threadIdx.x >> 6] = v;
    __syncthreads();
    return fmaxf(fmaxf(sm[0], sm[1]), fmaxf(sm[2], sm[3]));
}

// ---------------------------------------------------------------------------
// fp32 [R][C] -> bf16 [C][R] transpose+convert; batched via blockIdx.z (z*R*C)
// Optionally also emits the straight (non-transposed) bf16 copy into out2.
// ---------------------------------------------------------------------------
__global__ __launch_bounds__(256) void transpose_cvt(
    const float* __restrict__ in, ushort_t* __restrict__ out, int R, int C,
    ushort_t* __restrict__ out2) {
    __shared__ float tl[32][33];
    const size_t zoff = (size_t)blockIdx.z * R * C;
    const int tx = threadIdx.x & 31, ty = threadIdx.x >> 5;  // ty 0..7
    const int c0 = blockIdx.x * 32, r0 = blockIdx.y * 32;
#pragma unroll
    for (int i = 0; i < 4; i++) {
        const float v = in[zoff + (size_t)(r0 + ty + i * 8) * C + c0 + tx];
        tl[ty + i * 8][tx] = v;
        if (out2) out2[zoff + (size_t)(r0 + ty + i * 8) * C + c0 + tx] = f2bf(v);
    }
    __syncthreads();
#pragma unroll
    for (int i = 0; i < 4; i++)
        out[zoff + (size_t)(c0 + ty + i * 8) * R + r0 + tx] = f2bf(tl[tx][ty + i * 8]);
}

// ---------------------------------------------------------------------------
// Shared index preamble for 128-wide-M cores (4 waves)
// ---------------------------------------------------------------------------
#define IDX128()                                                               \
    const int t = threadIdx.x;                                                 \
    const int sr = t >> 2;               /* 0..63 */                           \
    const int sc = (t & 3) * 8;          /* 0,8,16,24 */                       \
    const int lane = t & 63, w = t >> 6;                                       \
    const int fr = lane & 15, fq = lane >> 4;

// MFMA stage from explicit LDS buffer pointers (128x128 core: 2x2 waves)
#define MFMA16(Asp, Bsp)                                                       \
    {                                                                          \
        short8 af[4], bfg[4];                                                  \
        _Pragma("unroll") for (int i = 0; i < 4; i++) {                        \
            af[i]  = *(const short8*)&(Asp)[(wm + i * 16 + fr) * 40 + fq * 8]; \
            bfg[i] = *(const short8*)&(Bsp)[(wn + i * 16 + fr) * 40 + fq * 8]; \
        }                                                                      \
        _Pragma("unroll") for (int i = 0; i < 4; i++)                          \
            _Pragma("unroll") for (int j = 0; j < 4; j++)                      \
                acc[i][j] = __builtin_amdgcn_mfma_f32_16x16x32_bf16(           \
                    af[i], bfg[j], acc[i][j], 0, 0, 0);                        \
    }

// MFMA stage for 128x64 core (4 waves stacked on M, wave tile 32x64)
#define MFMA8(Asp, Bsp)                                                        \
    {                                                                          \
        short8 af[2], bfg[4];                                                  \
        _Pragma("unroll") for (int i = 0; i < 2; i++)                          \
            af[i]  = *(const short8*)&(Asp)[(wm + i * 16 + fr) * 40 + fq * 8]; \
        _Pragma("unroll") for (int j = 0; j < 4; j++)                          \
            bfg[j] = *(const short8*)&(Bsp)[(j * 16 + fr) * 40 + fq * 8];      \
        _Pragma("unroll") for (int i = 0; i < 2; i++)                          \
            _Pragma("unroll") for (int j = 0; j < 4; j++)                      \
                acc[i][j] = __builtin_amdgcn_mfma_f32_16x16x32_bf16(           \
                    af[i], bfg[j], acc[i][j], 0, 0, 0);                        \
    }

// ---------------------------------------------------------------------------
// Gate GEMM: 128x128 tile, BK=32, double-buffered, XCD-swizzled.
// A = concat(NX,CD) fp32 (pack to bf16 at LDS-write time), B = WgT bf16.
// Epilogue: g = sigmoid(acc + bg); Fb = bf16(g*NX + (1-g)*CD). M=BS,N=512,K=1024
// ---------------------------------------------------------------------------
__global__ __launch_bounds__(256) void gate_gemm(
    const float* __restrict__ NX, const float* __restrict__ CD,
    const ushort_t* __restrict__ WgT, const float* __restrict__ bg,
    ushort_t* __restrict__ Fb) {
    __shared__ ushort_t As[2][128 * 40];
    __shared__ ushort_t Bs[2][128 * 40];
    SWZ_DECODE(bx, by, bz);
    (void)bz;
    IDX128();
    const int m0 = by * 128, n0 = bx * 128;
    const int wm = (w >> 1) * 64, wn = (w & 1) * 64;
    floatx4 acc[4][4];
#pragma unroll
    for (int i = 0; i < 4; i++)
#pragma unroll
        for (int j = 0; j < 4; j++) {
            acc[i][j][0] = 0.f; acc[i][j][1] = 0.f;
            acc[i][j][2] = 0.f; acc[i][j][3] = 0.f;
        }
    const ushort_t* Bb = WgT + (size_t)n0 * 1024;

    float4 f00, f01, f10, f11;
    int4 b0, b1;
    // k = 0 (NX): load + write buf0
    {
        const float* p0 = NX + (size_t)(m0 + sr) * 512 + sc;
        const float* p1 = NX + (size_t)(m0 + sr + 64) * 512 + sc;
        f00 = *(const float4*)p0;  f01 = *(const float4*)(p0 + 4);
        f10 = *(const float4*)p1;  f11 = *(const float4*)(p1 + 4);
        b0 = *(const int4*)(Bb + (size_t)sr * 1024 + sc);
        b1 = *(const int4*)(Bb + (size_t)(sr + 64) * 1024 + sc);
        *(short8*)&As[0][sr * 40 + sc] = pack8(f00, f01);
        *(short8*)&As[0][(sr + 64) * 40 + sc] = pack8(f10, f11);
        *(int4*)&Bs[0][sr * 40 + sc] = b0;
        *(int4*)&Bs[0][(sr + 64) * 40 + sc] = b1;
    }
    // k = 32 (NX): load into regs
    {
        const float* p0 = NX + (size_t)(m0 + sr) * 512 + 32 + sc;
        const float* p1 = NX + (size_t)(m0 + sr + 64) * 512 + 32 + sc;
        f00 = *(const float4*)p0;  f01 = *(const float4*)(p0 + 4);
        f10 = *(const float4*)p1;  f11 = *(const float4*)(p1 + 4);
        b0 = *(const int4*)(Bb + (size_t)sr * 1024 + 32 + sc);
        b1 = *(const int4*)(Bb + (size_t)(sr + 64) * 1024 + 32 + sc);
    }
    __syncthreads();

    int cur = 0;
    for (int k0 = 0; k0 < 1024; k0 += 32) {
        MFMA16(As[cur], Bs[cur]);
        const int kn = k0 + 32;
        if (kn < 1024) {
            *(short8*)&As[cur ^ 1][sr * 40 + sc] = pack8(f00, f01);
            *(short8*)&As[cur ^ 1][(sr + 64) * 40 + sc] = pack8(f10, f11);
            *(int4*)&Bs[cur ^ 1][sr * 40 + sc] = b0;
            *(int4*)&Bs[cur ^ 1][(sr + 64) * 40 + sc] = b1;
            const int kf = kn + 32;
            if (kf < 1024) {
                const float* Asrc = (kf < 512) ? NX : CD;
                const int kk = kf & 511;
                const float* p0 = Asrc + (size_t)(m0 + sr) * 512 + kk + sc;
                const float* p1 = Asrc + (size_t)(m0 + sr + 64) * 512 + kk + sc;
                f00 = *(const float4*)p0;  f01 = *(const float4*)(p0 + 4);
                f10 = *(const float4*)p1;  f11 = *(const float4*)(p1 + 4);
                b0 = *(const int4*)(Bb + (size_t)sr * 1024 + kf + sc);
                b1 = *(const int4*)(Bb + (size_t)(sr + 64) * 1024 + kf + sc);
            }
        }
        __syncthreads();
        cur ^= 1;
    }

#pragma unroll
    for (int i = 0; i < 4; i++) {
#pragma unroll
        for (int j = 0; j < 4; j++) {
#pragma unroll
            for (int r = 0; r < 4; r++) {
                const int m = m0 + wm + i * 16 + fq * 4 + r;
                const int n = n0 + wn + j * 16 + fr;
                const float z = acc[i][j][r] + bg[n];
                const float g = 1.f / (1.f + expf(-z));
                const size_t idx = (size_t)m * 512 + n;
                Fb[idx] = f2bf(g * NX[idx] + (1.f - g) * CD[idx]);
            }
        }
    }
}

// ---------------------------------------------------------------------------
// gemm2: 128x128 tile, BK=32, pure bf16, double-buffered, XCD-swizzled.
// For qk + ffn (grids >= 2 blocks/CU, LDS 40,960 B -> 4 blocks/CU).
// EPI: 0 = scale + bf16 store; 1 = +bias, exact gelu, bf16 store;
//      2 = fp32 accumulate in place (T += acc [+ bias if init])
// ---------------------------------------------------------------------------
template <int EPI>
__global__ __launch_bounds__(256) void gemm2_std(
    const ushort_t* __restrict__ A, int lda, long sAz,
    const ushort_t* __restrict__ Bt, int ldb, long sBz,
    void* __restrict__ Cv, int ldc, long sCz,
    int K, const float* __restrict__ bias, float scale, int init) {
    __shared__ ushort_t As[2][128 * 40];
    __shared__ ushort_t Bs[2][128 * 40];
    SWZ_DECODE(bx, by, bz);
    IDX128();
    const int m0 = by * 128, n0 = bx * 128;
    const int wm = (w >> 1) * 64, wn = (w & 1) * 64;
    floatx4 acc[4][4];
#pragma unroll
    for (int i = 0; i < 4; i++)
#pragma unroll
        for (int j = 0; j < 4; j++) {
            acc[i][j][0] = 0.f; acc[i][j][1] = 0.f;
            acc[i][j][2] = 0.f; acc[i][j][3] = 0.f;
        }
    const ushort_t* Ab = A + (size_t)bz * sAz + (size_t)m0 * lda;
    const ushort_t* Bb = Bt + (size_t)bz * sBz + (size_t)n0 * ldb;

    int4 a0 = *(const int4*)(Ab + (size_t)sr * lda + sc);
    int4 a1 = *(const int4*)(Ab + (size_t)(sr + 64) * lda + sc);
    int4 b0 = *(const int4*)(Bb + (size_t)sr * ldb + sc);
    int4 b1 = *(const int4*)(Bb + (size_t)(sr + 64) * ldb + sc);
    *(int4*)&As[0][sr * 40 + sc] = a0;
    *(int4*)&As[0][(sr + 64) * 40 + sc] = a1;
    *(int4*)&Bs[0][sr * 40 + sc] = b0;
    *(int4*)&Bs[0][(sr + 64) * 40 + sc] = b1;
    if (32 < K) {
        a0 = *(const int4*)(Ab + (size_t)sr * lda + 32 + sc);
        a1 = *(const int4*)(Ab + (size_t)(sr + 64) * lda + 32 + sc);
        b0 = *(const int4*)(Bb + (size_t)sr * ldb + 32 + sc);
        b1 = *(const int4*)(Bb + (size_t)(sr + 64) * ldb + 32 + sc);
    }
    __syncthreads();

    int cur = 0;
    for (int k0 = 0; k0 < K; k0 += 32) {
        MFMA16(As[cur], Bs[cur]);
        const int kn = k0 + 32;
        if (kn < K) {
            *(int4*)&As[cur ^ 1][sr * 40 + sc] = a0;
            *(int4*)&As[cur ^ 1][(sr + 64) * 40 + sc] = a1;
            *(int4*)&Bs[cur ^ 1][sr * 40 + sc] = b0;
            *(int4*)&Bs[cur ^ 1][(sr + 64) * 40 + sc] = b1;
            const int kf = kn + 32;
            if (kf < K) {
                a0 = *(const int4*)(Ab + (size_t)sr * lda + kf + sc);
                a1 = *(const int4*)(Ab + (size_t)(sr + 64) * lda + kf + sc);
                b0 = *(const int4*)(Bb + (size_t)sr * ldb + kf + sc);
                b1 = *(const int4*)(Bb + (size_t)(sr + 64) * ldb + kf + sc);
            }
        }
        __syncthreads();
        cur ^= 1;
    }

#pragma unroll
    for (int i = 0; i < 4; i++) {
#pragma unroll
        for (int j = 0; j < 4; j++) {
#pragma unroll
            for (int r = 0; r < 4; r++) {
                const int m = m0 + wm + i * 16 + fq * 4 + r;
                const int n = n0 + wn + j * 16 + fr;
                float v = acc[i][j][r];
                if (EPI == 0) {
                    ushort_t* C = (ushort_t*)Cv + (size_t)bz * sCz;
                    C[(size_t)m * ldc + n] = f2bf(v * scale);
                } else if (EPI == 1) {
                    const float x = v + bias[n];
                    const float gl = 0.5f * x * (1.f + erff(x * 0.70710678118654752f));
                    ushort_t* C = (ushort_t*)Cv;
                    C[(size_t)m * ldc + n] = f2bf(gl);
                } else {
                    float* T = (float*)Cv;
                    const size_t idx = (size_t)m * ldc + n;
                    T[idx] = T[idx] + v + (init ? bias[n] : 0.f);
                }
            }
        }
    }
}

// ---------------------------------------------------------------------------
// gemm3: 128x64 tile, BK=32, stride-40, double-buffered, XCD-swizzled.
// For PV (512 blocks = 2/CU). LDS 30,720 B. 4 waves stacked on M
// (wave tile 32x64). R10: reverted from R9's BK=64/stride-72 (8-way bank
// conflict, see header).
// ---------------------------------------------------------------------------
template <int EPI>
__global__ __launch_bounds__(256) void gemm3_std(
    const ushort_t* __restrict__ A, int lda, long sAz,
    const ushort_t* __restrict__ Bt, int ldb, long sBz,
    void* __restrict__ Cv, int ldc, long sCz,
    int K, const float* __restrict__ bias, float scale, int init) {
    __shared__ ushort_t As[2][128 * 40];
    __shared__ ushort_t Bs[2][64 * 40];
    SWZ_DECODE(bx, by, bz);
    IDX128();
    const int m0 = by * 128, n0 = bx * 64;
    const int wm = w * 32;
    floatx4 acc[2][4];
#pragma unroll
    for (int i = 0; i < 2; i++)
#pragma unroll
        for (int j = 0; j < 4; j++) {
            acc[i][j][0] = 0.f; acc[i][j][1] = 0.f;
            acc[i][j][2] = 0.f; acc[i][j][3] = 0.f;
        }
    const ushort_t* Ab = A + (size_t)bz * sAz + (size_t)m0 * lda;
    const ushort_t* Bb = Bt + (size_t)bz * sBz + (size_t)n0 * ldb;

    int4 a0 = *(const int4*)(Ab + (size_t)sr * lda + sc);
    int4 a1 = *(const int4*)(Ab + (size_t)(sr + 64) * lda + sc);
    int4 b0 = *(const int4*)(Bb + (size_t)sr * ldb + sc);
    *(int4*)&As[0][sr * 40 + sc] = a0;
    *(int4*)&As[0][(sr + 64) * 40 + sc] = a1;
    *(int4*)&Bs[0][sr * 40 + sc] = b0;
    if (32 < K) {
        a0 = *(const int4*)(Ab + (size_t)sr * lda + 32 + sc);
        a1 = *(const int4*)(Ab + (size_t)(sr + 64) * lda + 32 + sc);
        b0 = *(const int4*)(Bb + (size_t)sr * ldb + 32 + sc);
    }
    __syncthreads();

    int cur = 0;
    for (int k0 = 0; k0 < K; k0 += 32) {
        MFMA8(As[cur], Bs[cur]);
        const int kn = k0 + 32;
        if (kn < K) {
            *(int4*)&As[cur ^ 1][sr * 40 + sc] = a0;
            *(int4*)&As[cur ^ 1][(sr + 64) * 40 + sc] = a1;
            *(int4*)&Bs[cur ^ 1][sr * 40 + sc] = b0;
            const int kf = kn + 32;
            if (kf < K) {
                a0 = *(const int4*)(Ab + (size_t)sr * lda + kf + sc);
                a1 = *(const int4*)(Ab + (size_t)(sr + 64) * lda + kf + sc);
                b0 = *(const int4*)(Bb + (size_t)sr * ldb + kf + sc);
            }
        }
        __syncthreads();
        cur ^= 1;
    }

#pragma unroll
    for (int i = 0; i < 2; i++) {
#pragma unroll
        for (int j = 0; j < 4; j++) {
#pragma unroll
            for (int r = 0; r < 4; r++) {
                const int m = m0 + wm + i * 16 + fq * 4 + r;
                const int n = n0 + j * 16 + fr;
                float v = acc[i][j][r];
                if (EPI == 0) {
                    ushort_t* C = (ushort_t*)Cv + (size_t)bz * sCz;
                    C[(size_t)m * ldc + n] = f2bf(v * scale);
                } else if (EPI == 1) {
                    const float x = v + bias[n];
                    const float gl = 0.5f * x * (1.f + erff(x * 0.70710678118654752f));
                    ushort_t* C = (ushort_t*)Cv;
                    C[(size_t)m * ldc + n] = f2bf(gl);
                } else {
                    float* T = (float*)Cv;
                    const size_t idx = (size_t)m * ldc + n;
                    T[idx] = T[idx] + v + (init ? bias[n] : 0.f);
                }
            }
        }
    }
}

// ---------------------------------------------------------------------------
// Softmax over bf16 rows of 2048, in place
// ---------------------------------------------------------------------------
__global__ __launch_bounds__(256) void softmax_bf16(ushort_t* __restrict__ Sc) {
    __shared__ float sm[4];
    ushort_t* row = Sc + (size_t)blockIdx.x * 2048;
    const int t = threadIdx.x;
    ushort_t raw[8];
    *(int4*)raw = *(const int4*)(row + t * 8);
    float e[8];
    float mx = -1e30f;
#pragma unroll
    for (int j = 0; j < 8; j++) { e[j] = bf2f(raw[j]); mx = fmaxf(mx, e[j]); }
    mx = blk_reduce_max(mx, sm);
    float s = 0.f;
#pragma unroll
    for (int j = 0; j < 8; j++) { e[j] = expf(e[j] - mx); s += e[j]; }
    s = blk_reduce_sum(s, sm);
    const float inv = 1.f / s;
#pragma unroll
    for (int j = 0; j < 8; j++) raw[j] = f2bf(e[j] * inv);
    *(int4*)(row + t * 8) = *(const int4*)raw;
}

// ---------------------------------------------------------------------------
// LN1: q = LN(fused + attn) -> qf (fp32) and qb (bf16)
// ---------------------------------------------------------------------------
__global__ __launch_bounds__(256) void ln1_kernel(
    const ushort_t* __restrict__ Fb, const ushort_t* __restrict__ Ab,
    const float* __restrict__ g1, const float* __restrict__ be1,
    float* __restrict__ qf, ushort_t* __restrict__ qb) {
    __shared__ float sm[4];
    const size_t base = (size_t)blockIdx.x * 512;
    const int t = threadIdx.x;
    const float v0 = bf2f(Fb[base + t]) + bf2f(Ab[base + t]);
    const float v1 = bf2f(Fb[base + t + 256]) + bf2f(Ab[base + t + 256]);
    const float mu = blk_reduce_sum(v0 + v1, sm) * (1.f / 512.f);
    const float d0 = v0 - mu, d1 = v1 - mu;
    const float var = blk_reduce_sum(d0 * d0 + d1 * d1, sm) * (1.f / 512.f);
    const float rs = rsqrtf(var + LN_EPS);
    const float y0 = d0 * rs * g1[t] + be1[t];
    const float y1 = d1 * rs * g1[t + 256] + be1[t + 256];
    qf[base + t] = y0;          qf[base + t + 256] = y1;
    qb[base + t] = f2bf(y0);    qb[base + t + 256] = f2bf(y1);
}

// Final LN in place on fp32
__global__ __launch_bounds__(256) void ln2_kernel(
    float* __restrict__ T, const float* __restrict__ g,
    const float* __restrict__ be) {
    __shared__ float sm[4];
    const size_t base = (size_t)blockIdx.x * 512;
    const int t = threadIdx.x;
    const float v0 = T[base + t];
    const float v1 = T[base + t + 256];
    const float mu = blk_reduce_sum(v0 + v1, sm) * (1.f / 512.f);
    const float d0 = v0 - mu, d1 = v1 - mu;
    const float var = blk_reduce_sum(d0 * d0 + d1 * d1, sm) * (1.f / 512.f);
    const float rs = rsqrtf(var + LN_EPS);
    T[base + t] = d0 * rs * g[t] + be[t];
    T[base + t + 256] = d1 * rs * g[t + 256] + be[t + 256];
}

// ---------------------------------------------------------------------------
extern "C" void kernel_launch(void* const* d_in, const int* in_sizes, int n_in,
                              void* d_out, int out_size, void* d_ws, size_t ws_size,
                              hipStream_t stream) {
    const float* NX  = (const float*)d_in[0];
    const float* X   = (const float*)d_in[1];
    const float* CD  = (const float*)d_in[2];
    const float* Wg  = (const float*)d_in[3];
    const float* bg  = (const float*)d_in[4];
    const float* W1  = (const float*)d_in[5];
    const float* b1  = (const float*)d_in[6];
    const float* W2  = (const float*)d_in[7];
    const float* b2  = (const float*)d_in[8];
    const float* g1  = (const float*)d_in[9];
    const float* be1 = (const float*)d_in[10];
    const float* g2  = (const float*)d_in[11];
    const float* be2 = (const float*)d_in[12];

    // ws: 3 slots x 16,777,216 B = 50,331,648 B (proven-safe since R2)
    // slot0: Xb -> attnb (progressive, see header note) -> hbuf
    // slot1: Fb -> W1T/W2T;  slot2: WgT -> XbT -> qb
    // d_out: scores (bf16) -> qf (fp32, final)
    ushort_t* slot0 = (ushort_t*)d_ws;
    ushort_t* slot1 = (ushort_t*)((char*)d_ws + 16777216);
    ushort_t* slot2 = (ushort_t*)((char*)d_ws + 33554432);
    ushort_t* Xb    = slot0;                    // [8][2048][512] bf16
    ushort_t* attnb = slot0;
    ushort_t* hbuf  = slot0;
    ushort_t* Fb    = slot1;
    ushort_t* W1T   = slot1;                    // [1024][512] bf16, 1 MB
    ushort_t* W2T   = slot1 + 524288;           // [512][1024] bf16, 1 MB
    ushort_t* WgT   = slot2;                    // [512][1024] bf16, 1 MB
    ushort_t* XbT   = slot2;                    // [8][512][2048] bf16, 16.78 MB
    ushort_t* qb    = slot2;                    // [BS][512] bf16
    ushort_t* Scb   = (ushort_t*)d_out;         // 4 batches [S][S] bf16
    float*    qf    = (float*)d_out;

    // 1) Wg^T (slot2)
    transpose_cvt<<<dim3(512 / 32, 1024 / 32, 1), 256, 0, stream>>>(
        Wg, WgT, 1024, 512, nullptr);

    // 2) gated fusion -> Fb (128x128 dbuf core; fp32 A converted in staging)
    gate_gemm<<<dim3(4, 128), 256, 0, stream>>>(NX, CD, WgT, bg, Fb);

    // 3) X^T per batch into slot2 (WgT dead) — needed by PV;
    //    fused straight bf16 copy Xb into slot0 — needed by QK
    transpose_cvt<<<dim3(512 / 32, 2048 / 32, 8), 256, 0, stream>>>(
        X, XbT, 2048, 512, Xb);

    // 4) attention in 2 groups of 4 batches; scores in d_out
    for (int g = 0; g < 2; g++) {
        const size_t go = (size_t)g * 4 * S * 512;
        // QK: Sc = (Fb @ Xb^T) * scale (128x128 dbuf; 1024 blocks = 4/CU)
        gemm2_std<0><<<dim3(16, 16, 4), 256, 0, stream>>>(
            Fb + go, D, (long)S * D,
            Xb + go, D, (long)S * D,
            (void*)Scb, S, (long)S * S, D, nullptr, ATTN_SCALE, 0);
        softmax_bf16<<<4 * S, 256, 0, stream>>>(Scb);
        // PV: attn = P @ X  (128x64 BK=32 dbuf; 512 blocks = 2/CU)
        gemm3_std<0><<<dim3(8, 16, 4), 256, 0, stream>>>(
            Scb, S, (long)S * S,
            XbT + go, S, (long)D * S,
            (void*)(attnb + go), 512, (long)S * 512, S, nullptr, 1.f, 0);
    }

    // 5) q = LN(fused + attn): qf -> d_out (scores dead), qb -> slot2 (XbT dead)
    ln1_kernel<<<BS, 256, 0, stream>>>(Fb, attnb, g1, be1, qf, qb);

    // 6) weight transposes into slot1 (Fb dead after LN1)
    transpose_cvt<<<dim3(1024 / 32, 512 / 32, 1), 256, 0, stream>>>(
        W1, W1T, 512, 1024, nullptr);
    transpose_cvt<<<dim3(512 / 32, 1024 / 32, 1), 256, 0, stream>>>(
        W2, W2T, 1024, 512, nullptr);

    // 7) FFN in 2 halves; hidden half in slot0 (attnb dead); t accumulates in d_out
    for (int h = 0; h < 2; h++) {
        gemm2_std<1><<<dim3(4, 128), 256, 0, stream>>>(
            qb, 512, 0, W1T + (size_t)h * 512 * 512, 512, 0,
            (void*)hbuf, 512, 0, 512, b1 + h * 512, 1.f, 0);
        gemm2_std<2><<<dim3(4, 128), 256, 0, stream>>>(
            hbuf, 512, 0, W2T + h * 512, 1024, 0,
            (void*)qf, 512, 0, 512, b2, 1.f, h == 0 ? 1 : 0);
    }

    // 8) out = LN(t) in place in d_out
    ln2_kernel<<<BS, 256, 0, stream>>>(qf, g2, be2);
}

// Round 6
// 468.745 us; speedup vs baseline: 1.2861x; 1.0955x over previous
//
#include <hip/hip_runtime.h>
#include <math.h>

typedef unsigned short ushort_t;
typedef unsigned int uint_t;
typedef __attribute__((ext_vector_type(8))) short short8;
typedef __attribute__((ext_vector_type(4))) float floatx4;

// Problem dims
constexpr int B = 8;
constexpr int S = 2048;
constexpr int D = 512;
constexpr int BS = B * S;          // 16384 rows
constexpr float LN_EPS = 1e-5f;
constexpr float ATTN_SCALE = 0.04419417382415922f;  // 1/sqrt(512)

// R5: no global_load_lds (replay corruption). R6: PV at 1 block/CU starves.
// R7: reg-prefetch alone neutral. R8 (539): single-barrier dbuf +6us only.
// R9 (603): T1 XCD swizzle GOOD (gate FETCH 164->66 MB confirmed R10); PV
// stride-72 8-way bank conflict BAD. R10 (513): swizzle + stride-40 dbuf
// everywhere. Gate now: Occ 18%, Mfma 12%, VALU 38%, HBM 19% -> latency-
// bound at 8 waves/CU (512-block grids = 2 blocks/CU grid cap x 4 waves).
// R11: 512-thread (8-wave) blocks for gate+gemm2 at the same 128x128 tile:
// 16 waves/CU at the same grid; per-thread staging halves (1 A + 1 B int4;
// gate pack8 16->8 f2bf). Wave grid 2M x 4N, wave-tile 64x32, acc[4][2],
// 8 MFMA/step/wave. PV keeps proven 256-thread gemm3.
// (gate SQ_LDS_BANK_CONFLICT == 2^22 every round = artifact, ignore.)
// Xb aliasing (slot0): qk g reads batches of Xb that pv g-1 hasn't
// overwritten; stream-ordered => safe.

// ---------------------------------------------------------------------------
// bf16 helpers (RNE)
// ---------------------------------------------------------------------------
__device__ __forceinline__ ushort_t f2bf(float f) {
    union { float f; uint_t u; } x; x.f = f;
    uint_t r = x.u + 0x7fffu + ((x.u >> 16) & 1u);
    return (ushort_t)(r >> 16);
}
__device__ __forceinline__ float bf2f(ushort_t h) {
    union { uint_t u; float f; } y; y.u = ((uint_t)h) << 16;
    return y.f;
}
__device__ __forceinline__ short8 pack8(float4 a, float4 b) {
    short8 p;
    p[0] = (short)f2bf(a.x); p[1] = (short)f2bf(a.y);
    p[2] = (short)f2bf(a.z); p[3] = (short)f2bf(a.w);
    p[4] = (short)f2bf(b.x); p[5] = (short)f2bf(b.y);
    p[6] = (short)f2bf(b.z); p[7] = (short)f2bf(b.w);
    return p;
}

// XCD-aware bijective swizzle (T1): flat id F -> logical tile L so that each
// XCD (F%8) owns a contiguous chunk of logical tiles. Requires nwg%8==0
// (all GEMM grids here: 512/1024). Decode x-fastest.
#define SWZ_DECODE(bx, by, bz)                                                 \
    int bx, by, bz;                                                            \
    {                                                                          \
        const int gx = gridDim.x, gy = gridDim.y;                              \
        const int nwg = gx * gy * (int)gridDim.z;                              \
        const int F = blockIdx.x + gx * (blockIdx.y + gy * blockIdx.z);        \
        const int L = (F & 7) * (nwg >> 3) + (F >> 3);                         \
        bx = L % gx;                                                           \
        const int l2 = L / gx;                                                 \
        by = l2 % gy;                                                          \
        bz = l2 / gy;                                                          \
    }

// ---------------------------------------------------------------------------
// Reductions (256-thread blocks = 4 waves of 64)
// ---------------------------------------------------------------------------
__device__ __forceinline__ float blk_reduce_sum(float v, float* sm) {
#pragma unroll
    for (int o = 32; o; o >>= 1) v += __shfl_down(v, o, 64);
    __syncthreads();
    if ((threadIdx.x & 63) == 0) sm[threadIdx.x >> 6] = v;
    __syncthreads();
    return sm[0] + sm[1] + sm[2] + sm[3];
}
__device__ __forceinline__ float blk_reduce_max(float v, float* sm) {
#pragma unroll
    for (int o = 32; o; o >>= 1) v = fmaxf(v, __shfl_down(v, o, 64));
    __syncthreads();
    if ((threadIdx.x & 63) == 0) sm[threadIdx.x >> 6] = v;
    __syncthreads();
    return fmaxf(fmaxf(sm[0], sm[1]), fmaxf(sm[2], sm[3]));
}

// ---------------------------------------------------------------------------
// fp32 [R][C] -> bf16 [C][R] transpose+convert; batched via blockIdx.z (z*R*C)
// Optionally also emits the straight (non-transposed) bf16 copy into out2.
// ---------------------------------------------------------------------------
__global__ __launch_bounds__(256) void transpose_cvt(
    const float* __restrict__ in, ushort_t* __restrict__ out, int R, int C,
    ushort_t* __restrict__ out2) {
    __shared__ float tl[32][33];
    const size_t zoff = (size_t)blockIdx.z * R * C;
    const int tx = threadIdx.x & 31, ty = threadIdx.x >> 5;  // ty 0..7
    const int c0 = blockIdx.x * 32, r0 = blockIdx.y * 32;
#pragma unroll
    for (int i = 0; i < 4; i++) {
        const float v = in[zoff + (size_t)(r0 + ty + i * 8) * C + c0 + tx];
        tl[ty + i * 8][tx] = v;
        if (out2) out2[zoff + (size_t)(r0 + ty + i * 8) * C + c0 + tx] = f2bf(v);
    }
    __syncthreads();
#pragma unroll
    for (int i = 0; i < 4; i++)
        out[zoff + (size_t)(c0 + ty + i * 8) * R + r0 + tx] = f2bf(tl[tx][ty + i * 8]);
}

// ---------------------------------------------------------------------------
// 8-wave (512-thread) 128x128 core preamble: wave grid 2M x 4N, wave-tile
// 64x32, acc[4][2]. Staging: each thread 1 int4 per operand (srow 0..127).
// ---------------------------------------------------------------------------
#define IDX512()                                                               \
    const int t = threadIdx.x;                                                 \
    const int srow = t >> 2;             /* 0..127 */                          \
    const int scol = (t & 3) * 8;        /* 0,8,16,24 */                       \
    const int lane = t & 63, w = t >> 6; /* w 0..7 */                          \
    const int wm = (w >> 2) * 64, wn = (w & 3) * 32;                           \
    const int fr = lane & 15, fq = lane >> 4;

// MFMA stage for the 8-wave core: 8 MFMA per K-step per wave
#define MFMA8W(Asp, Bsp)                                                       \
    {                                                                          \
        short8 af[4], bfg[2];                                                  \
        _Pragma("unroll") for (int i = 0; i < 4; i++)                          \
            af[i]  = *(const short8*)&(Asp)[(wm + i * 16 + fr) * 40 + fq * 8]; \
        _Pragma("unroll") for (int j = 0; j < 2; j++)                          \
            bfg[j] = *(const short8*)&(Bsp)[(wn + j * 16 + fr) * 40 + fq * 8]; \
        _Pragma("unroll") for (int i = 0; i < 4; i++)                          \
            _Pragma("unroll") for (int j = 0; j < 2; j++)                      \
                acc[i][j] = __builtin_amdgcn_mfma_f32_16x16x32_bf16(           \
                    af[i], bfg[j], acc[i][j], 0, 0, 0);                        \
    }

// ---------------------------------------------------------------------------
// Gate GEMM: 128x128 tile, BK=32, dbuf, XCD-swizzled, 8 waves.
// A = concat(NX,CD) fp32 (pack to bf16 at LDS-write time), B = WgT bf16.
// Epilogue: g = sigmoid(acc + bg); Fb = bf16(g*NX + (1-g)*CD). M=BS,N=512,K=1024
// ---------------------------------------------------------------------------
__global__ __launch_bounds__(512) void gate_gemm(
    const float* __restrict__ NX, const float* __restrict__ CD,
    const ushort_t* __restrict__ WgT, const float* __restrict__ bg,
    ushort_t* __restrict__ Fb) {
    __shared__ ushort_t As[2][128 * 40];
    __shared__ ushort_t Bs[2][128 * 40];
    SWZ_DECODE(bx, by, bz);
    (void)bz;
    IDX512();
    const int m0 = by * 128, n0 = bx * 128;
    floatx4 acc[4][2];
#pragma unroll
    for (int i = 0; i < 4; i++)
#pragma unroll
        for (int j = 0; j < 2; j++) {
            acc[i][j][0] = 0.f; acc[i][j][1] = 0.f;
            acc[i][j][2] = 0.f; acc[i][j][3] = 0.f;
        }
    const ushort_t* Bb = WgT + (size_t)n0 * 1024;

    float4 fa0, fa1;
    int4 b0;
    // k = 0 (NX): load + write buf0
    {
        const float* p0 = NX + (size_t)(m0 + srow) * 512 + scol;
        fa0 = *(const float4*)p0;  fa1 = *(const float4*)(p0 + 4);
        b0 = *(const int4*)(Bb + (size_t)srow * 1024 + scol);
        *(short8*)&As[0][srow * 40 + scol] = pack8(fa0, fa1);
        *(int4*)&Bs[0][srow * 40 + scol] = b0;
    }
    // k = 32 (NX): load into regs
    {
        const float* p0 = NX + (size_t)(m0 + srow) * 512 + 32 + scol;
        fa0 = *(const float4*)p0;  fa1 = *(const float4*)(p0 + 4);
        b0 = *(const int4*)(Bb + (size_t)srow * 1024 + 32 + scol);
    }
    __syncthreads();

    int cur = 0;
    for (int k0 = 0; k0 < 1024; k0 += 32) {
        MFMA8W(As[cur], Bs[cur]);
        const int kn = k0 + 32;
        if (kn < 1024) {
            *(short8*)&As[cur ^ 1][srow * 40 + scol] = pack8(fa0, fa1);
            *(int4*)&Bs[cur ^ 1][srow * 40 + scol] = b0;
            const int kf = kn + 32;
            if (kf < 1024) {
                const float* Asrc = (kf < 512) ? NX : CD;
                const int kk = kf & 511;
                const float* p0 = Asrc + (size_t)(m0 + srow) * 512 + kk + scol;
                fa0 = *(const float4*)p0;  fa1 = *(const float4*)(p0 + 4);
                b0 = *(const int4*)(Bb + (size_t)srow * 1024 + kf + scol);
            }
        }
        __syncthreads();
        cur ^= 1;
    }

#pragma unroll
    for (int i = 0; i < 4; i++) {
#pragma unroll
        for (int j = 0; j < 2; j++) {
#pragma unroll
            for (int r = 0; r < 4; r++) {
                const int m = m0 + wm + i * 16 + fq * 4 + r;
                const int n = n0 + wn + j * 16 + fr;
                const float z = acc[i][j][r] + bg[n];
                const float g = 1.f / (1.f + expf(-z));
                const size_t idx = (size_t)m * 512 + n;
                Fb[idx] = f2bf(g * NX[idx] + (1.f - g) * CD[idx]);
            }
        }
    }
}

// ---------------------------------------------------------------------------
// gemm2: 128x128 tile, BK=32, pure bf16, dbuf, XCD-swizzled, 8 waves.
// For qk + ffn. LDS 40,960 B.
// EPI: 0 = scale + bf16 store; 1 = +bias, exact gelu, bf16 store;
//      2 = fp32 accumulate in place (T += acc [+ bias if init])
// ---------------------------------------------------------------------------
template <int EPI>
__global__ __launch_bounds__(512) void gemm2_std(
    const ushort_t* __restrict__ A, int lda, long sAz,
    const ushort_t* __restrict__ Bt, int ldb, long sBz,
    void* __restrict__ Cv, int ldc, long sCz,
    int K, const float* __restrict__ bias, float scale, int init) {
    __shared__ ushort_t As[2][128 * 40];
    __shared__ ushort_t Bs[2][128 * 40];
    SWZ_DECODE(bx, by, bz);
    IDX512();
    const int m0 = by * 128, n0 = bx * 128;
    floatx4 acc[4][2];
#pragma unroll
    for (int i = 0; i < 4; i++)
#pragma unroll
        for (int j = 0; j < 2; j++) {
            acc[i][j][0] = 0.f; acc[i][j][1] = 0.f;
            acc[i][j][2] = 0.f; acc[i][j][3] = 0.f;
        }
    const ushort_t* Ab = A + (size_t)bz * sAz + (size_t)m0 * lda;
    const ushort_t* Bb = Bt + (size_t)bz * sBz + (size_t)n0 * ldb;

    int4 a0 = *(const int4*)(Ab + (size_t)srow * lda + scol);
    int4 b0 = *(const int4*)(Bb + (size_t)srow * ldb + scol);
    *(int4*)&As[0][srow * 40 + scol] = a0;
    *(int4*)&Bs[0][srow * 40 + scol] = b0;
    if (32 < K) {
        a0 = *(const int4*)(Ab + (size_t)srow * lda + 32 + scol);
        b0 = *(const int4*)(Bb + (size_t)srow * ldb + 32 + scol);
    }
    __syncthreads();

    int cur = 0;
    for (int k0 = 0; k0 < K; k0 += 32) {
        MFMA8W(As[cur], Bs[cur]);
        const int kn = k0 + 32;
        if (kn < K) {
            *(int4*)&As[cur ^ 1][srow * 40 + scol] = a0;
            *(int4*)&Bs[cur ^ 1][srow * 40 + scol] = b0;
            const int kf = kn + 32;
            if (kf < K) {
                a0 = *(const int4*)(Ab + (size_t)srow * lda + kf + scol);
                b0 = *(const int4*)(Bb + (size_t)srow * ldb + kf + scol);
            }
        }
        __syncthreads();
        cur ^= 1;
    }

#pragma unroll
    for (int i = 0; i < 4; i++) {
#pragma unroll
        for (int j = 0; j < 2; j++) {
#pragma unroll
            for (int r = 0; r < 4; r++) {
                const int m = m0 + wm + i * 16 + fq * 4 + r;
                const int n = n0 + wn + j * 16 + fr;
                float v = acc[i][j][r];
                if (EPI == 0) {
                    ushort_t* C = (ushort_t*)Cv + (size_t)bz * sCz;
                    C[(size_t)m * ldc + n] = f2bf(v * scale);
                } else if (EPI == 1) {
                    const float x = v + bias[n];
                    const float gl = 0.5f * x * (1.f + erff(x * 0.70710678118654752f));
                    ushort_t* C = (ushort_t*)Cv;
                    C[(size_t)m * ldc + n] = f2bf(gl);
                } else {
                    float* T = (float*)Cv;
                    const size_t idx = (size_t)m * ldc + n;
                    T[idx] = T[idx] + v + (init ? bias[n] : 0.f);
                }
            }
        }
    }
}

// ---------------------------------------------------------------------------
// gemm3: 128x64 tile, BK=32, stride-40, dbuf, XCD-swizzled, 256 threads.
// For PV (512 blocks = 2/CU). LDS 30,720 B. 4 waves stacked on M
// (wave tile 32x64). Proven core (R10).
// ---------------------------------------------------------------------------
#define IDX128()                                                               \
    const int t = threadIdx.x;                                                 \
    const int sr = t >> 2;               /* 0..63 */                           \
    const int sc = (t & 3) * 8;          /* 0,8,16,24 */                       \
    const int lane = t & 63, w = t >> 6;                                       \
    const int fr = lane & 15, fq = lane >> 4;

#define MFMA8(Asp, Bsp)                                                        \
    {                                                                          \
        short8 af[2], bfg[4];                                                  \
        _Pragma("unroll") for (int i = 0; i < 2; i++)                          \
            af[i]  = *(const short8*)&(Asp)[(wm + i * 16 + fr) * 40 + fq * 8]; \
        _Pragma("unroll") for (int j = 0; j < 4; j++)                          \
            bfg[j] = *(const short8*)&(Bsp)[(j * 16 + fr) * 40 + fq * 8];      \
        _Pragma("unroll") for (int i = 0; i < 2; i++)                          \
            _Pragma("unroll") for (int j = 0; j < 4; j++)                      \
                acc[i][j] = __builtin_amdgcn_mfma_f32_16x16x32_bf16(           \
                    af[i], bfg[j], acc[i][j], 0, 0, 0);                        \
    }

template <int EPI>
__global__ __launch_bounds__(256) void gemm3_std(
    const ushort_t* __restrict__ A, int lda, long sAz,
    const ushort_t* __restrict__ Bt, int ldb, long sBz,
    void* __restrict__ Cv, int ldc, long sCz,
    int K, const float* __restrict__ bias, float scale, int init) {
    __shared__ ushort_t As[2][128 * 40];
    __shared__ ushort_t Bs[2][64 * 40];
    SWZ_DECODE(bx, by, bz);
    IDX128();
    const int m0 = by * 128, n0 = bx * 64;
    const int wm = w * 32;
    floatx4 acc[2][4];
#pragma unroll
    for (int i = 0; i < 2; i++)
#pragma unroll
        for (int j = 0; j < 4; j++) {
            acc[i][j][0] = 0.f; acc[i][j][1] = 0.f;
            acc[i][j][2] = 0.f; acc[i][j][3] = 0.f;
        }
    const ushort_t* Ab = A + (size_t)bz * sAz + (size_t)m0 * lda;
    const ushort_t* Bb = Bt + (size_t)bz * sBz + (size_t)n0 * ldb;

    int4 a0 = *(const int4*)(Ab + (size_t)sr * lda + sc);
    int4 a1 = *(const int4*)(Ab + (size_t)(sr + 64) * lda + sc);
    int4 b0 = *(const int4*)(Bb + (size_t)sr * ldb + sc);
    *(int4*)&As[0][sr * 40 + sc] = a0;
    *(int4*)&As[0][(sr + 64) * 40 + sc] = a1;
    *(int4*)&Bs[0][sr * 40 + sc] = b0;
    if (32 < K) {
        a0 = *(const int4*)(Ab + (size_t)sr * lda + 32 + sc);
        a1 = *(const int4*)(Ab + (size_t)(sr + 64) * lda + 32 + sc);
        b0 = *(const int4*)(Bb + (size_t)sr * ldb + 32 + sc);
    }
    __syncthreads();

    int cur = 0;
    for (int k0 = 0; k0 < K; k0 += 32) {
        MFMA8(As[cur], Bs[cur]);
        const int kn = k0 + 32;
        if (kn < K) {
            *(int4*)&As[cur ^ 1][sr * 40 + sc] = a0;
            *(int4*)&As[cur ^ 1][(sr + 64) * 40 + sc] = a1;
            *(int4*)&Bs[cur ^ 1][sr * 40 + sc] = b0;
            const int kf = kn + 32;
            if (kf < K) {
                a0 = *(const int4*)(Ab + (size_t)sr * lda + kf + sc);
                a1 = *(const int4*)(Ab + (size_t)(sr + 64) * lda + kf + sc);
                b0 = *(const int4*)(Bb + (size_t)sr * ldb + kf + sc);
            }
        }
        __syncthreads();
        cur ^= 1;
    }

#pragma unroll
    for (int i = 0; i < 2; i++) {
#pragma unroll
        for (int j = 0; j < 4; j++) {
#pragma unroll
            for (int r = 0; r < 4; r++) {
                const int m = m0 + wm + i * 16 + fq * 4 + r;
                const int n = n0 + j * 16 + fr;
                float v = acc[i][j][r];
                if (EPI == 0) {
                    ushort_t* C = (ushort_t*)Cv + (size_t)bz * sCz;
                    C[(size_t)m * ldc + n] = f2bf(v * scale);
                } else if (EPI == 1) {
                    const float x = v + bias[n];
                    const float gl = 0.5f * x * (1.f + erff(x * 0.70710678118654752f));
                    ushort_t* C = (ushort_t*)Cv;
                    C[(size_t)m * ldc + n] = f2bf(gl);
                } else {
                    float* T = (float*)Cv;
                    const size_t idx = (size_t)m * ldc + n;
                    T[idx] = T[idx] + v + (init ? bias[n] : 0.f);
                }
            }
        }
    }
}

// ---------------------------------------------------------------------------
// Softmax over bf16 rows of 2048, in place
// ---------------------------------------------------------------------------
__global__ __launch_bounds__(256) void softmax_bf16(ushort_t* __restrict__ Sc) {
    __shared__ float sm[4];
    ushort_t* row = Sc + (size_t)blockIdx.x * 2048;
    const int t = threadIdx.x;
    ushort_t raw[8];
    *(int4*)raw = *(const int4*)(row + t * 8);
    float e[8];
    float mx = -1e30f;
#pragma unroll
    for (int j = 0; j < 8; j++) { e[j] = bf2f(raw[j]); mx = fmaxf(mx, e[j]); }
    mx = blk_reduce_max(mx, sm);
    float s = 0.f;
#pragma unroll
    for (int j = 0; j < 8; j++) { e[j] = expf(e[j] - mx); s += e[j]; }
    s = blk_reduce_sum(s, sm);
    const float inv = 1.f / s;
#pragma unroll
    for (int j = 0; j < 8; j++) raw[j] = f2bf(e[j] * inv);
    *(int4*)(row + t * 8) = *(const int4*)raw;
}

// ---------------------------------------------------------------------------
// LN1: q = LN(fused + attn) -> qf (fp32) and qb (bf16)
// ---------------------------------------------------------------------------
__global__ __launch_bounds__(256) void ln1_kernel(
    const ushort_t* __restrict__ Fb, const ushort_t* __restrict__ Ab,
    const float* __restrict__ g1, const float* __restrict__ be1,
    float* __restrict__ qf, ushort_t* __restrict__ qb) {
    __shared__ float sm[4];
    const size_t base = (size_t)blockIdx.x * 512;
    const int t = threadIdx.x;
    const float v0 = bf2f(Fb[base + t]) + bf2f(Ab[base + t]);
    const float v1 = bf2f(Fb[base + t + 256]) + bf2f(Ab[base + t + 256]);
    const float mu = blk_reduce_sum(v0 + v1, sm) * (1.f / 512.f);
    const float d0 = v0 - mu, d1 = v1 - mu;
    const float var = blk_reduce_sum(d0 * d0 + d1 * d1, sm) * (1.f / 512.f);
    const float rs = rsqrtf(var + LN_EPS);
    const float y0 = d0 * rs * g1[t] + be1[t];
    const float y1 = d1 * rs * g1[t + 256] + be1[t + 256];
    qf[base + t] = y0;          qf[base + t + 256] = y1;
    qb[base + t] = f2bf(y0);    qb[base + t + 256] = f2bf(y1);
}

// Final LN in place on fp32
__global__ __launch_bounds__(256) void ln2_kernel(
    float* __restrict__ T, const float* __restrict__ g,
    const float* __restrict__ be) {
    __shared__ float sm[4];
    const size_t base = (size_t)blockIdx.x * 512;
    const int t = threadIdx.x;
    const float v0 = T[base + t];
    const float v1 = T[base + t + 256];
    const float mu = blk_reduce_sum(v0 + v1, sm) * (1.f / 512.f);
    const float d0 = v0 - mu, d1 = v1 - mu;
    const float var = blk_reduce_sum(d0 * d0 + d1 * d1, sm) * (1.f / 512.f);
    const float rs = rsqrtf(var + LN_EPS);
    T[base + t] = d0 * rs * g[t] + be[t];
    T[base + t + 256] = d1 * rs * g[t + 256] + be[t + 256];
}

// ---------------------------------------------------------------------------
extern "C" void kernel_launch(void* const* d_in, const int* in_sizes, int n_in,
                              void* d_out, int out_size, void* d_ws, size_t ws_size,
                              hipStream_t stream) {
    const float* NX  = (const float*)d_in[0];
    const float* X   = (const float*)d_in[1];
    const float* CD  = (const float*)d_in[2];
    const float* Wg  = (const float*)d_in[3];
    const float* bg  = (const float*)d_in[4];
    const float* W1  = (const float*)d_in[5];
    const float* b1  = (const float*)d_in[6];
    const float* W2  = (const float*)d_in[7];
    const float* b2  = (const float*)d_in[8];
    const float* g1  = (const float*)d_in[9];
    const float* be1 = (const float*)d_in[10];
    const float* g2  = (const float*)d_in[11];
    const float* be2 = (const float*)d_in[12];

    // ws: 3 slots x 16,777,216 B = 50,331,648 B (proven-safe since R2)
    // slot0: Xb -> attnb (progressive, see header note) -> hbuf
    // slot1: Fb -> W1T/W2T;  slot2: WgT -> XbT -> qb
    // d_out: scores (bf16) -> qf (fp32, final)
    ushort_t* slot0 = (ushort_t*)d_ws;
    ushort_t* slot1 = (ushort_t*)((char*)d_ws + 16777216);
    ushort_t* slot2 = (ushort_t*)((char*)d_ws + 33554432);
    ushort_t* Xb    = slot0;                    // [8][2048][512] bf16
    ushort_t* attnb = slot0;
    ushort_t* hbuf  = slot0;
    ushort_t* Fb    = slot1;
    ushort_t* W1T   = slot1;                    // [1024][512] bf16, 1 MB
    ushort_t* W2T   = slot1 + 524288;           // [512][1024] bf16, 1 MB
    ushort_t* WgT   = slot2;                    // [512][1024] bf16, 1 MB
    ushort_t* XbT   = slot2;                    // [8][512][2048] bf16, 16.78 MB
    ushort_t* qb    = slot2;                    // [BS][512] bf16
    ushort_t* Scb   = (ushort_t*)d_out;         // 4 batches [S][S] bf16
    float*    qf    = (float*)d_out;

    // 1) Wg^T (slot2)
    transpose_cvt<<<dim3(512 / 32, 1024 / 32, 1), 256, 0, stream>>>(
        Wg, WgT, 1024, 512, nullptr);

    // 2) gated fusion -> Fb (128x128 dbuf 8-wave core)
    gate_gemm<<<dim3(4, 128), 512, 0, stream>>>(NX, CD, WgT, bg, Fb);

    // 3) X^T per batch into slot2 (WgT dead) — needed by PV;
    //    fused straight bf16 copy Xb into slot0 — needed by QK
    transpose_cvt<<<dim3(512 / 32, 2048 / 32, 8), 256, 0, stream>>>(
        X, XbT, 2048, 512, Xb);

    // 4) attention in 2 groups of 4 batches; scores in d_out
    for (int g = 0; g < 2; g++) {
        const size_t go = (size_t)g * 4 * S * 512;
        // QK: Sc = (Fb @ Xb^T) * scale (128x128 dbuf 8-wave; 1024 blocks)
        gemm2_std<0><<<dim3(16, 16, 4), 512, 0, stream>>>(
            Fb + go, D, (long)S * D,
            Xb + go, D, (long)S * D,
            (void*)Scb, S, (long)S * S, D, nullptr, ATTN_SCALE, 0);
        softmax_bf16<<<4 * S, 256, 0, stream>>>(Scb);
        // PV: attn = P @ X  (128x64 BK=32 dbuf; 512 blocks = 2/CU)
        gemm3_std<0><<<dim3(8, 16, 4), 256, 0, stream>>>(
            Scb, S, (long)S * S,
            XbT + go, S, (long)D * S,
            (void*)(attnb + go), 512, (long)S * 512, S, nullptr, 1.f, 0);
    }

    // 5) q = LN(fused + attn): qf -> d_out (scores dead), qb -> slot2 (XbT dead)
    ln1_kernel<<<BS, 256, 0, stream>>>(Fb, attnb, g1, be1, qf, qb);

    // 6) weight transposes into slot1 (Fb dead after LN1)
    transpose_cvt<<<dim3(1024 / 32, 512 / 32, 1), 256, 0, stream>>>(
        W1, W1T, 512, 1024, nullptr);
    transpose_cvt<<<dim3(512 / 32, 1024 / 32, 1), 256, 0, stream>>>(
        W2, W2T, 1024, 512, nullptr);

    // 7) FFN in 2 halves; hidden half in slot0 (attnb dead); t accumulates in d_out
    for (int h = 0; h < 2; h++) {
        gemm2_std<1><<<dim3(4, 128), 512, 0, stream>>>(
            qb, 512, 0, W1T + (size_t)h * 512 * 512, 512, 0,
            (void*)hbuf, 512, 0, 512, b1 + h * 512, 1.f, 0);
        gemm2_std<2><<<dim3(4, 128), 512, 0, stream>>>(
            hbuf, 512, 0, W2T + h * 512, 1024, 0,
            (void*)qf, 512, 0, 512, b2, 1.f, h == 0 ? 1 : 0);
    }

    // 8) out = LN(t) in place in d_out
    ln2_kernel<<<BS, 256, 0, stream>>>(qf, g2, be2);
}